// Round 4
// baseline (446.672 us; speedup 1.0000x reference)
//
#include <hip/hip_runtime.h>
#include <math.h>

#define T_N     4096
#define B_N     64
#define C_N     64
#define NFILT   2
#define F_BINS  2049
#define NPAIRS  2016
#define NFEAT   4032
#define NOUT    4
#define TSG     4
#define NKS     32            // (4096/TSG)/32 K-steps per gram block

#define PI_F 3.14159265358979323846f

typedef _Float16 f16x8 __attribute__((ext_vector_type(8)));
typedef float    f32x4 __attribute__((ext_vector_type(4)));

// ---------------------------------------------------------------------------
// Spectrum layout of the 3-phase register FFT (N = 16*16*16):
//   thread t = k1*16 + j1, register q = j2  holds bin k = q*256 + j1*16 + k1.
// Filter table is stored at position p = q*256 + t matching that layout:
//   p(k) = (k & 0xF00) + ((k & 15) << 4) + ((k >> 4) & 15)
// ---------------------------------------------------------------------------

// ---------------- filter construction (1 block) ----------------
__global__ __launch_bounds__(256) void filter_kernel(
    const float* __restrict__ fm_, const float* __restrict__ bw_,
    const float* __restrict__ sp_, const float* __restrict__ gd_,
    float* __restrict__ filt) {
  __shared__ float smag[F_BINS];
  __shared__ float sred[256];
  const int tid = threadIdx.x;
  for (int f = 0; f < NFILT; ++f) {
    float* Fre = filt + f * 8192;
    float* Fim = Fre + 4096;
    for (int p = tid; p < 4096; p += 256) { Fre[p] = 0.0f; Fim[p] = 0.0f; }
    const float fm = fminf(fmaxf(fm_[f], 1.0f / 128.0f), 45.0f / 128.0f);
    const float bw = fminf(fmaxf(bw_[f], 1.0f / 128.0f), 1.0f);
    const float pp = fminf(fmaxf(sp_[f], 2.0f), 3.0f) * 8.0f - 14.0f;
    const float gd = gd_[f];
    const float scale = bw / (2.0f * powf(0.69314718055994531f, 1.0f / pp));
    float lmax = 0.0f;
    for (int i = tid; i < F_BINS; i += 256) {
      const float n = (float)i / 2048.0f;
      const float m = expf(-powf((fabsf(n - fm) + 1e-8f) / scale, pp));
      smag[i] = m;
      lmax = fmaxf(lmax, m);
    }
    sred[tid] = lmax;
    __syncthreads();
    for (int s = 128; s > 0; s >>= 1) {
      if (tid < s) sred[tid] = fmaxf(sred[tid], sred[tid + s]);
      __syncthreads();
    }
    const float inv = 1.0f / sred[0];
    __syncthreads();
    for (int k = tid; k < F_BINS; k += 256) {
      const float m = smag[k] * inv;
      const float pha = -gd * ((float)k * 0.125f) * PI_F;
      float sn, cs;
      sincosf(pha, &sn, &cs);
      const float dcs = (k == 0) ? 1.0f : 2.0f;
      const float sT = dcs * (1.0f / (float)T_N);
      const int p = (k & 0xF00) + ((k & 15) << 4) + ((k >> 4) & 15);
      Fre[p] = m * cs * sT;
      Fim[p] = m * sn * sT;
    }
    __syncthreads();
  }
}

// ---------------- 16-point DFT, natural order in/out, in registers ----------
// SGN=-1: forward (W = e^{-2pi i/16}); SGN=+1: inverse (unscaled, conj)
template<int SGN>
__device__ __forceinline__ void dft16(float* __restrict__ vr,
                                      float* __restrict__ vi) {
  const float sg = (float)SGN;
  const float C1 = 0.923879532511287f, S1 = 0.382683432365090f;
  const float Hh = 0.707106781186548f;
  float gr[16], gi[16];
#pragma unroll
  for (int n2 = 0; n2 < 4; ++n2) {
    const float ar = vr[n2],      ai = vi[n2];
    const float br = vr[4 + n2],  bi = vi[4 + n2];
    const float cr = vr[8 + n2],  ci = vi[8 + n2];
    const float dr = vr[12 + n2], di = vi[12 + n2];
    const float t0r = ar + cr, t0i = ai + ci;
    const float t1r = ar - cr, t1i = ai - ci;
    const float t2r = br + dr, t2i = bi + di;
    const float t3r = br - dr, t3i = bi - di;
    gr[n2]      = t0r + t2r;      gi[n2]      = t0i + t2i;       // k1=0
    gr[4 + n2]  = t1r - sg * t3i; gi[4 + n2]  = t1i + sg * t3r;  // k1=1
    gr[8 + n2]  = t0r - t2r;      gi[8 + n2]  = t0i - t2i;       // k1=2
    gr[12 + n2] = t1r + sg * t3i; gi[12 + n2] = t1i - sg * t3r;  // k1=3
  }
  // twiddle g[k1*4+n2] *= (cos, sg*sin)(pi*n2*k1/8)
#define TW16(idx, wr_, wi_) { const float xr = gr[idx], xi = gi[idx]; \
    gr[idx] = xr * (wr_) - xi * (wi_); gi[idx] = xr * (wi_) + xi * (wr_); }
  TW16(5,  C1,  sg * S1)                                   // nk=1
  TW16(6,  Hh,  sg * Hh)                                   // nk=2
  TW16(7,  S1,  sg * C1)                                   // nk=3
  TW16(9,  Hh,  sg * Hh)                                   // nk=2
  { const float xr = gr[10], xi = gi[10];                  // nk=4: *(0, sg)
    gr[10] = -sg * xi; gi[10] = sg * xr; }
  TW16(11, -Hh, sg * Hh)                                   // nk=6
  TW16(13, S1,  sg * C1)                                   // nk=3
  TW16(14, -Hh, sg * Hh)                                   // nk=6
  TW16(15, -C1, -sg * S1)                                  // nk=9
#undef TW16
#pragma unroll
  for (int k1 = 0; k1 < 4; ++k1) {
    const float ar = gr[4 * k1],     ai = gi[4 * k1];
    const float br = gr[4 * k1 + 1], bi = gi[4 * k1 + 1];
    const float cr = gr[4 * k1 + 2], ci = gi[4 * k1 + 2];
    const float dr = gr[4 * k1 + 3], di = gi[4 * k1 + 3];
    const float t0r = ar + cr, t0i = ai + ci;
    const float t1r = ar - cr, t1i = ai - ci;
    const float t2r = br + dr, t2i = bi + di;
    const float t3r = br - dr, t3i = bi - di;
    vr[k1]      = t0r + t2r;      vi[k1]      = t0i + t2i;
    vr[4 + k1]  = t1r - sg * t3i; vi[4 + k1]  = t1i + sg * t3r;
    vr[8 + k1]  = t0r - t2r;      vi[8 + k1]  = t0i - t2i;
    vr[12 + k1] = t1r + sg * t3i; vi[12 + k1] = t1i - sg * t3r;
  }
}

// cumulative twiddle chain: v[k] *= w^k, k=1..15, w=(cs,sn)
__device__ __forceinline__ void twchain(float* __restrict__ vr,
                                        float* __restrict__ vi,
                                        float cs, float sn) {
  float cr = cs, ci = sn;
#pragma unroll
  for (int k = 1; k < 16; ++k) {
    const float xr = vr[k], xi = vi[k];
    vr[k] = xr * cr - xi * ci;
    vi[k] = xr * ci + xi * cr;
    const float nr = cr * cs - ci * sn, ni = cr * sn + ci * cs;
    cr = nr; ci = ni;
  }
}

// transposes through padded float2 LDS (stride 264 -> all accesses ~2-way)
__device__ __forceinline__ void tr_cross_fwd(float* __restrict__ vr,
                                             float* __restrict__ vi,
                                             float2* __restrict__ lds, int t) {
  __syncthreads();
#pragma unroll
  for (int k = 0; k < 16; ++k) lds[k * 264 + t] = make_float2(vr[k], vi[k]);
  __syncthreads();
  const int base = (t >> 4) * 264 + (t & 15);
#pragma unroll
  for (int m = 0; m < 16; ++m) {
    const float2 v = lds[base + m * 16];
    vr[m] = v.x; vi[m] = v.y;
  }
}
__device__ __forceinline__ void tr_cross_inv(float* __restrict__ vr,
                                             float* __restrict__ vi,
                                             float2* __restrict__ lds, int t) {
  __syncthreads();
  const int base = (t >> 4) * 264 + (t & 15);
#pragma unroll
  for (int m = 0; m < 16; ++m) lds[base + m * 16] = make_float2(vr[m], vi[m]);
  __syncthreads();
#pragma unroll
  for (int k = 0; k < 16; ++k) {
    const float2 v = lds[k * 264 + t];
    vr[k] = v.x; vi[k] = v.y;
  }
}
// transpose within each 16-thread group, +r rotation kills bank conflicts
__device__ __forceinline__ void tr_group(float* __restrict__ vr,
                                         float* __restrict__ vi,
                                         float2* __restrict__ lds, int t) {
  __syncthreads();
  const int k1 = t >> 4, s = t & 15;
  const int rowb = k1 * 264;
#pragma unroll
  for (int r = 0; r < 16; ++r)
    lds[rowb + r * 16 + ((s + r) & 15)] = make_float2(vr[r], vi[r]);
  __syncthreads();
#pragma unroll
  for (int a = 0; a < 16; ++a) {
    const float2 v = lds[rowb + s * 16 + ((a + s) & 15)];
    vr[a] = v.x; vi[a] = v.y;
  }
}

// ---------------- forward FFT + filter + inverse FFT + normalize -> f16 ------
__global__ __launch_bounds__(256, 4) void fftfilt_kernel(
    const float* __restrict__ x, const float* __restrict__ filt,
    _Float16* __restrict__ Urg, _Float16* __restrict__ Uig, int chunkbase) {
  const int bb = blockIdx.x >> 6;
  const int c  = blockIdx.x & 63;
  const int b  = chunkbase + bb;
  const int t  = threadIdx.x;
  __shared__ float2 lds[16 * 264];   // 33792 B

  float vr[16], vi[16];
  const float* xp = x + ((size_t)(b * C_N + c)) * T_N;
#pragma unroll
  for (int r = 0; r < 16; ++r) { vr[r] = xp[r * 256 + t]; vi[r] = 0.0f; }

  // ---- forward: DFT16 over r, twiddle W4096^(t*k1), cross-T, DFT16,
  //      twiddle W256^(m2*j1), group-T, DFT16 ----
  dft16<-1>(vr, vi);
  {
    float sn, cs;
    sincosf(-2.0f * PI_F * (float)t * (1.0f / 4096.0f), &sn, &cs);
    twchain(vr, vi, cs, sn);
  }
  tr_cross_fwd(vr, vi, lds, t);
  dft16<-1>(vr, vi);
  {
    float sn, cs;
    sincosf(-2.0f * PI_F * (float)(t & 15) * (1.0f / 256.0f), &sn, &cs);
    twchain(vr, vi, cs, sn);
  }
  tr_group(vr, vi, lds, t);
  dft16<-1>(vr, vi);

  float Xr[16], Xi[16];
#pragma unroll
  for (int q = 0; q < 16; ++q) { Xr[q] = vr[q]; Xi[q] = vi[q]; }

#pragma unroll 1
  for (int f = 0; f < NFILT; ++f) {
    const float* Fre = filt + f * 8192;
    const float* Fim = Fre + 4096;
#pragma unroll
    for (int q = 0; q < 16; ++q) {
      vr[q] = Xr[q] * Fre[q * 256 + t];   // component-wise (permuted order)
      vi[q] = Xi[q] * Fim[q * 256 + t];
    }
    // ---- inverse (mirror dataflow, conj twiddles, unscaled) ----
    dft16<1>(vr, vi);
    {
      float sn, cs;
      sincosf(2.0f * PI_F * (float)(t & 15) * (1.0f / 256.0f), &sn, &cs);
      twchain(vr, vi, cs, sn);
    }
    tr_group(vr, vi, lds, t);
    dft16<1>(vr, vi);
    {
      const int k1 = t >> 4, m2 = t & 15;
      float snb, csb, sno, cso;
      sincosf(2.0f * PI_F * (float)k1 * (1.0f / 256.0f), &snb, &csb);
      sincosf(2.0f * PI_F * (float)(k1 * m2) * (1.0f / 4096.0f), &sno, &cso);
      float cr = cso, ci = sno;
#pragma unroll
      for (int m1 = 0; m1 < 16; ++m1) {
        const float xr = vr[m1], xi = vi[m1];
        vr[m1] = xr * cr - xi * ci;
        vi[m1] = xr * ci + xi * cr;
        const float nr = cr * csb - ci * snb, ni = cr * snb + ci * csb;
        cr = nr; ci = ni;
      }
    }
    tr_cross_inv(vr, vi, lds, t);
    dft16<1>(vr, vi);

    const int sl = bb * 2 + f;
    _Float16* upr = Urg + ((size_t)sl * C_N + c) * T_N;
    _Float16* upi = Uig + ((size_t)sl * C_N + c) * T_N;
#pragma unroll
    for (int n1 = 0; n1 < 16; ++n1) {
      const float ir = rsqrtf(vr[n1] * vr[n1] + vi[n1] * vi[n1] + 1e-6f);
      upr[n1 * 256 + t] = (_Float16)(vr[n1] * ir);
      upi[n1 * 256 + t] = (_Float16)(vi[n1] * ir);
    }
  }
}

// ---------------- gram via f16 MFMA: Rr=UrUr^T, Ii=UiUi^T, Ri=UrUi^T ---------
__global__ __launch_bounds__(256) void gram_kernel(
    const _Float16* __restrict__ Urg, const _Float16* __restrict__ Uig,
    float* __restrict__ G, int slicebase) {
  const int sl = blockIdx.x >> 2;           // / TSG
  const int ts = blockIdx.x & (TSG - 1);
  const int tid = threadIdx.x;
  const int w = tid >> 6;
  const int lane = tid & 63;
  __shared__ _Float16 sUr[2][64 * 40], sUi[2][64 * 40];

  const int row = tid >> 2, quarter = tid & 3;
  const size_t goff = (size_t)sl * C_N * T_N + (size_t)row * T_N
                      + ts * (T_N / TSG) + quarter * 8;
  const int loff = row * 40 + quarter * 8;
  const int frow = (lane & 15) * 40 + (lane >> 4) * 8;
  const int aoff = w * 640 + frow;

  f32x4 accRr[4] = {}, accIi[4] = {}, accRi[4] = {};

  f16x8 rr = *(const f16x8*)&Urg[goff];
  f16x8 ri = *(const f16x8*)&Uig[goff];
  int cur = 0;
  for (int ks = 0; ks < NKS; ++ks) {
    *(f16x8*)&sUr[cur][loff] = rr;
    *(f16x8*)&sUi[cur][loff] = ri;
    if (ks + 1 < NKS) {
      rr = *(const f16x8*)&Urg[goff + (ks + 1) * 32];
      ri = *(const f16x8*)&Uig[goff + (ks + 1) * 32];
    }
    __syncthreads();
    const f16x8 ar = *(const f16x8*)&sUr[cur][aoff];
    const f16x8 ai = *(const f16x8*)&sUi[cur][aoff];
#pragma unroll
    for (int n = 0; n < 4; ++n) {
      const f16x8 br = *(const f16x8*)&sUr[cur][n * 640 + frow];
      const f16x8 bi = *(const f16x8*)&sUi[cur][n * 640 + frow];
      accRr[n] = __builtin_amdgcn_mfma_f32_16x16x32_f16(ar, br, accRr[n], 0, 0, 0);
      accIi[n] = __builtin_amdgcn_mfma_f32_16x16x32_f16(ai, bi, accIi[n], 0, 0, 0);
      accRi[n] = __builtin_amdgcn_mfma_f32_16x16x32_f16(ar, bi, accRi[n], 0, 0, 0);
    }
    cur ^= 1;
  }

  float* Gs = G + (size_t)(slicebase + sl) * 12288;
  const int r0 = w * 16 + (lane >> 4) * 4;
  const int c0 = lane & 15;
#pragma unroll
  for (int n = 0; n < 4; ++n) {
    const bool upper = (n >= w);   // skip strictly-below-diagonal Rr/Ii tiles
#pragma unroll
    for (int e = 0; e < 4; ++e) {
      const int idx = (r0 + e) * 64 + n * 16 + c0;
      if (upper) {
        atomicAdd(&Gs[idx], accRr[n][e]);
        atomicAdd(&Gs[4096 + idx], accIi[n][e]);
      }
      atomicAdd(&Gs[8192 + idx], accRi[n][e]);
    }
  }
}

// ---------------- PLV + scatter to feature layout ----------------
__global__ __launch_bounds__(256) void plv_kernel(
    const float* __restrict__ G, float* __restrict__ feats) {
  const int idx = blockIdx.x * 256 + threadIdx.x;
  if (idx >= B_N * NFILT * NPAIRS) return;
  const int slice = idx / NPAIRS;
  const int p = idx - slice * NPAIRS;
  const int b = slice >> 1, f = slice & 1;
  int c = 0, rem = p;
  while (rem >= 63 - c) { rem -= 63 - c; ++c; }
  const int d = c + 1 + rem;
  const float* Gs = G + (size_t)slice * 12288;
  const float cre = Gs[c * 64 + d] + Gs[4096 + c * 64 + d];        // rr + ii
  const float cim = Gs[8192 + c * 64 + d] - Gs[8192 + d * 64 + c]; // ri - ir
  const float plv = sqrtf(cre * cre + cim * cim + 1e-6f) * (1.0f / (float)T_N);
  feats[b * NFEAT + p * NFILT + f] = plv;
}

// ---------------- batch stats (training-mode BN, biased var) ----------------
__global__ __launch_bounds__(256) void stats_kernel(
    const float* __restrict__ feats, float* __restrict__ stats) {
  const int j = blockIdx.x * 256 + threadIdx.x;
  if (j >= NFEAT) return;
  float s = 0.0f;
  for (int b = 0; b < B_N; ++b) s += feats[b * NFEAT + j];
  const float mu = s * (1.0f / (float)B_N);
  float v = 0.0f;
  for (int b = 0; b < B_N; ++b) {
    const float d = feats[b * NFEAT + j] - mu;
    v += d * d;
  }
  v *= (1.0f / (float)B_N);
  stats[j] = mu;
  stats[NFEAT + j] = 1.0f / sqrtf(v + 1e-5f);
}

// ---------------- normalize + linear ----------------
__global__ __launch_bounds__(256) void out_kernel(
    const float* __restrict__ feats, const float* __restrict__ stats,
    const float* __restrict__ w, const float* __restrict__ lb,
    float* __restrict__ out) {
  const int b = blockIdx.x;
  const int tid = threadIdx.x;
  float acc0 = 0, acc1 = 0, acc2 = 0, acc3 = 0;
  for (int j = tid; j < NFEAT; j += 256) {
    const float v = (feats[b * NFEAT + j] - stats[j]) * stats[NFEAT + j];
    acc0 += v * w[0 * NFEAT + j];
    acc1 += v * w[1 * NFEAT + j];
    acc2 += v * w[2 * NFEAT + j];
    acc3 += v * w[3 * NFEAT + j];
  }
  __shared__ float red[4][256];
  red[0][tid] = acc0; red[1][tid] = acc1; red[2][tid] = acc2; red[3][tid] = acc3;
  __syncthreads();
  for (int s = 128; s > 0; s >>= 1) {
    if (tid < s) {
#pragma unroll
      for (int o = 0; o < 4; ++o) red[o][tid] += red[o][tid + s];
    }
    __syncthreads();
  }
  if (tid < 4) out[b * NOUT + tid] = red[tid][0] + lb[tid];
}

extern "C" void kernel_launch(void* const* d_in, const int* in_sizes, int n_in,
                              void* d_out, int out_size, void* d_ws, size_t ws_size,
                              hipStream_t stream) {
  const float* x  = (const float*)d_in[0];
  const float* fm = (const float*)d_in[1];
  const float* bw = (const float*)d_in[2];
  const float* sp = (const float*)d_in[3];
  const float* gd = (const float*)d_in[4];
  const float* lw = (const float*)d_in[5];
  const float* lb = (const float*)d_in[6];
  float* out = (float*)d_out;
  char* base = (char*)d_ws;

  // adaptive batch chunk: largest of {64,32,16} whose u-buffer fits ws
  const size_t fixed = 65536 + 6291456 + (size_t)B_N * NFEAT * 4 + 2 * NFEAT * 4;
  int CB = 64;
  if (ws_size < fixed + (size_t)64 * 2097152) CB = 32;
  if (ws_size < fixed + (size_t)32 * 2097152) CB = 16;
  const int nchunk = B_N / CB;

  const size_t u_bytes = (size_t)CB * 1048576;  // per component array
  float*    filt  = (float*)base;
  _Float16* Urg   = (_Float16*)(base + 65536);
  _Float16* Uig   = (_Float16*)(base + 65536 + u_bytes);
  float*    G     = (float*)(base + 65536 + 2 * u_bytes);
  float*    feats = (float*)(base + 65536 + 2 * u_bytes + 6291456);
  float*    stats = feats + (size_t)B_N * NFEAT;

  hipMemsetAsync(G, 0, 6291456, stream);
  filter_kernel<<<1, 256, 0, stream>>>(fm, bw, sp, gd, filt);

  for (int chunk = 0; chunk < nchunk; ++chunk) {
    fftfilt_kernel<<<CB * C_N, 256, 0, stream>>>(x, filt, Urg, Uig, chunk * CB);
    gram_kernel<<<CB * 2 * TSG, 256, 0, stream>>>(Urg, Uig, G, chunk * CB * 2);
  }

  plv_kernel<<<(B_N * NFILT * NPAIRS + 255) / 256, 256, 0, stream>>>(G, feats);
  stats_kernel<<<(NFEAT + 255) / 256, 256, 0, stream>>>(feats, stats);
  out_kernel<<<B_N, 256, 0, stream>>>(feats, stats, lw, lb, out);
}

// Round 5
// 203.693 us; speedup vs baseline: 2.1929x; 2.1929x over previous
//
#include <hip/hip_runtime.h>
#include <math.h>

#define T_N     4096
#define B_N     64
#define C_N     64
#define NFILT   2
#define F_BINS  2049
#define NPAIRS  2016
#define NFEAT   4032
#define NOUT    4
#define TSG     4
#define NKS     32            // (4096/TSG)/32 K-steps per gram block

#define PI_F 3.14159265358979323846f

typedef _Float16 f16x8 __attribute__((ext_vector_type(8)));
typedef float    f32x4 __attribute__((ext_vector_type(4)));

// ---------------------------------------------------------------------------
// Spectrum layout of the 3-phase register FFT (N = 16*16*16):
//   thread t = k1*16 + j1, register q = j2  holds bin k = q*256 + j1*16 + k1.
// Filter table is stored at position p = q*256 + t matching that layout:
//   p(k) = (k & 0xF00) + ((k & 15) << 4) + ((k >> 4) & 15)
// ---------------------------------------------------------------------------

// ---------------- filter construction (1 block) ----------------
__global__ __launch_bounds__(256) void filter_kernel(
    const float* __restrict__ fm_, const float* __restrict__ bw_,
    const float* __restrict__ sp_, const float* __restrict__ gd_,
    float* __restrict__ filt) {
  __shared__ float smag[F_BINS];
  __shared__ float sred[256];
  const int tid = threadIdx.x;
  for (int f = 0; f < NFILT; ++f) {
    float* Fre = filt + f * 8192;
    float* Fim = Fre + 4096;
    for (int p = tid; p < 4096; p += 256) { Fre[p] = 0.0f; Fim[p] = 0.0f; }
    const float fm = fminf(fmaxf(fm_[f], 1.0f / 128.0f), 45.0f / 128.0f);
    const float bw = fminf(fmaxf(bw_[f], 1.0f / 128.0f), 1.0f);
    const float pp = fminf(fmaxf(sp_[f], 2.0f), 3.0f) * 8.0f - 14.0f;
    const float gd = gd_[f];
    const float scale = bw / (2.0f * powf(0.69314718055994531f, 1.0f / pp));
    float lmax = 0.0f;
    for (int i = tid; i < F_BINS; i += 256) {
      const float n = (float)i / 2048.0f;
      const float m = expf(-powf((fabsf(n - fm) + 1e-8f) / scale, pp));
      smag[i] = m;
      lmax = fmaxf(lmax, m);
    }
    sred[tid] = lmax;
    __syncthreads();
    for (int s = 128; s > 0; s >>= 1) {
      if (tid < s) sred[tid] = fmaxf(sred[tid], sred[tid + s]);
      __syncthreads();
    }
    const float inv = 1.0f / sred[0];
    __syncthreads();
    for (int k = tid; k < F_BINS; k += 256) {
      const float m = smag[k] * inv;
      const float pha = -gd * ((float)k * 0.125f) * PI_F;
      float sn, cs;
      sincosf(pha, &sn, &cs);
      const float dcs = (k == 0) ? 1.0f : 2.0f;
      const float sT = dcs * (1.0f / (float)T_N);
      const int p = (k & 0xF00) + ((k & 15) << 4) + ((k >> 4) & 15);
      Fre[p] = m * cs * sT;
      Fim[p] = m * sn * sT;
    }
    __syncthreads();
  }
}

// ---------------- 16-point DFT, natural order in/out, in registers ----------
// SGN=-1: forward (W = e^{-2pi i/16}); SGN=+1: inverse (unscaled, conj)
template<int SGN>
__device__ __forceinline__ void dft16(float* __restrict__ vr,
                                      float* __restrict__ vi) {
  const float sg = (float)SGN;
  const float C1 = 0.923879532511287f, S1 = 0.382683432365090f;
  const float Hh = 0.707106781186548f;
  float gr[16], gi[16];
#pragma unroll
  for (int n2 = 0; n2 < 4; ++n2) {
    const float ar = vr[n2],      ai = vi[n2];
    const float br = vr[4 + n2],  bi = vi[4 + n2];
    const float cr = vr[8 + n2],  ci = vi[8 + n2];
    const float dr = vr[12 + n2], di = vi[12 + n2];
    const float t0r = ar + cr, t0i = ai + ci;
    const float t1r = ar - cr, t1i = ai - ci;
    const float t2r = br + dr, t2i = bi + di;
    const float t3r = br - dr, t3i = bi - di;
    gr[n2]      = t0r + t2r;      gi[n2]      = t0i + t2i;       // k1=0
    gr[4 + n2]  = t1r - sg * t3i; gi[4 + n2]  = t1i + sg * t3r;  // k1=1
    gr[8 + n2]  = t0r - t2r;      gi[8 + n2]  = t0i - t2i;       // k1=2
    gr[12 + n2] = t1r + sg * t3i; gi[12 + n2] = t1i - sg * t3r;  // k1=3
  }
  // twiddle g[k1*4+n2] *= (cos, sg*sin)(pi*n2*k1/8)
#define TW16(idx, wr_, wi_) { const float xr = gr[idx], xi = gi[idx]; \
    gr[idx] = xr * (wr_) - xi * (wi_); gi[idx] = xr * (wi_) + xi * (wr_); }
  TW16(5,  C1,  sg * S1)                                   // nk=1
  TW16(6,  Hh,  sg * Hh)                                   // nk=2
  TW16(7,  S1,  sg * C1)                                   // nk=3
  TW16(9,  Hh,  sg * Hh)                                   // nk=2
  { const float xr = gr[10], xi = gi[10];                  // nk=4: *(0, sg)
    gr[10] = -sg * xi; gi[10] = sg * xr; }
  TW16(11, -Hh, sg * Hh)                                   // nk=6
  TW16(13, S1,  sg * C1)                                   // nk=3
  TW16(14, -Hh, sg * Hh)                                   // nk=6
  TW16(15, -C1, -sg * S1)                                  // nk=9
#undef TW16
#pragma unroll
  for (int k1 = 0; k1 < 4; ++k1) {
    const float ar = gr[4 * k1],     ai = gi[4 * k1];
    const float br = gr[4 * k1 + 1], bi = gi[4 * k1 + 1];
    const float cr = gr[4 * k1 + 2], ci = gi[4 * k1 + 2];
    const float dr = gr[4 * k1 + 3], di = gi[4 * k1 + 3];
    const float t0r = ar + cr, t0i = ai + ci;
    const float t1r = ar - cr, t1i = ai - ci;
    const float t2r = br + dr, t2i = bi + di;
    const float t3r = br - dr, t3i = bi - di;
    vr[k1]      = t0r + t2r;      vi[k1]      = t0i + t2i;
    vr[4 + k1]  = t1r - sg * t3i; vi[4 + k1]  = t1i + sg * t3r;
    vr[8 + k1]  = t0r - t2r;      vi[8 + k1]  = t0i - t2i;
    vr[12 + k1] = t1r + sg * t3i; vi[12 + k1] = t1i - sg * t3r;
  }
}

// cumulative twiddle chain: v[k] *= w^k, k=1..15, w=(cs,sn)
__device__ __forceinline__ void twchain(float* __restrict__ vr,
                                        float* __restrict__ vi,
                                        float cs, float sn) {
  float cr = cs, ci = sn;
#pragma unroll
  for (int k = 1; k < 16; ++k) {
    const float xr = vr[k], xi = vi[k];
    vr[k] = xr * cr - xi * ci;
    vi[k] = xr * ci + xi * cr;
    const float nr = cr * cs - ci * sn, ni = cr * sn + ci * cs;
    cr = nr; ci = ni;
  }
}

// transposes through padded float2 LDS (stride 264 -> all accesses ~2-way)
__device__ __forceinline__ void tr_cross_fwd(float* __restrict__ vr,
                                             float* __restrict__ vi,
                                             float2* __restrict__ lds, int t) {
  __syncthreads();
#pragma unroll
  for (int k = 0; k < 16; ++k) lds[k * 264 + t] = make_float2(vr[k], vi[k]);
  __syncthreads();
  const int base = (t >> 4) * 264 + (t & 15);
#pragma unroll
  for (int m = 0; m < 16; ++m) {
    const float2 v = lds[base + m * 16];
    vr[m] = v.x; vi[m] = v.y;
  }
}
__device__ __forceinline__ void tr_cross_inv(float* __restrict__ vr,
                                             float* __restrict__ vi,
                                             float2* __restrict__ lds, int t) {
  __syncthreads();
  const int base = (t >> 4) * 264 + (t & 15);
#pragma unroll
  for (int m = 0; m < 16; ++m) lds[base + m * 16] = make_float2(vr[m], vi[m]);
  __syncthreads();
#pragma unroll
  for (int k = 0; k < 16; ++k) {
    const float2 v = lds[k * 264 + t];
    vr[k] = v.x; vi[k] = v.y;
  }
}
// transpose within each 16-thread group, +r rotation kills bank conflicts
__device__ __forceinline__ void tr_group(float* __restrict__ vr,
                                         float* __restrict__ vi,
                                         float2* __restrict__ lds, int t) {
  __syncthreads();
  const int k1 = t >> 4, s = t & 15;
  const int rowb = k1 * 264;
#pragma unroll
  for (int r = 0; r < 16; ++r)
    lds[rowb + r * 16 + ((s + r) & 15)] = make_float2(vr[r], vi[r]);
  __syncthreads();
#pragma unroll
  for (int a = 0; a < 16; ++a) {
    const float2 v = lds[rowb + s * 16 + ((a + s) & 15)];
    vr[a] = v.x; vi[a] = v.y;
  }
}

// ---------------- forward FFT + filter + inverse FFT + normalize -> f16 ------
// ONE filter per block (halves per-thread register state vs caching spectrum;
// avoids the round-4 scratch-spill disaster). No min-waves bound: let the
// allocator take ~112-128 VGPRs, LDS 33.8 KB still gives >=2 blocks/CU.
__global__ __launch_bounds__(256) void fftfilt_kernel(
    const float* __restrict__ x, const float* __restrict__ filt,
    _Float16* __restrict__ Urg, _Float16* __restrict__ Uig, int chunkbase) {
  const int f  = blockIdx.x & 1;
  const int c  = (blockIdx.x >> 1) & 63;
  const int bb = blockIdx.x >> 7;
  const int b  = chunkbase + bb;
  const int t  = threadIdx.x;
  __shared__ float2 lds[16 * 264];   // 33792 B

  float vr[16], vi[16];
  const float* xp = x + ((size_t)(b * C_N + c)) * T_N;
#pragma unroll
  for (int r = 0; r < 16; ++r) { vr[r] = xp[r * 256 + t]; vi[r] = 0.0f; }

  // ---- forward: DFT16 over r, twiddle W4096^(t*k1), cross-T, DFT16,
  //      twiddle W256^(m2*j1), group-T, DFT16 ----
  dft16<-1>(vr, vi);
  {
    float sn, cs;
    sincosf(-2.0f * PI_F * (float)t * (1.0f / 4096.0f), &sn, &cs);
    twchain(vr, vi, cs, sn);
  }
  tr_cross_fwd(vr, vi, lds, t);
  dft16<-1>(vr, vi);
  {
    float sn, cs;
    sincosf(-2.0f * PI_F * (float)(t & 15) * (1.0f / 256.0f), &sn, &cs);
    twchain(vr, vi, cs, sn);
  }
  tr_group(vr, vi, lds, t);
  dft16<-1>(vr, vi);

  // ---- component-wise filter, in place (permuted order matches layout) ----
  {
    const float* Fre = filt + f * 8192;
    const float* Fim = Fre + 4096;
#pragma unroll
    for (int q = 0; q < 16; ++q) {
      vr[q] = vr[q] * Fre[q * 256 + t];
      vi[q] = vi[q] * Fim[q * 256 + t];
    }
  }

  // ---- inverse (mirror dataflow, conj twiddles, unscaled) ----
  dft16<1>(vr, vi);
  {
    float sn, cs;
    sincosf(2.0f * PI_F * (float)(t & 15) * (1.0f / 256.0f), &sn, &cs);
    twchain(vr, vi, cs, sn);
  }
  tr_group(vr, vi, lds, t);
  dft16<1>(vr, vi);
  {
    const int k1 = t >> 4, m2 = t & 15;
    float snb, csb, sno, cso;
    sincosf(2.0f * PI_F * (float)k1 * (1.0f / 256.0f), &snb, &csb);
    sincosf(2.0f * PI_F * (float)(k1 * m2) * (1.0f / 4096.0f), &sno, &cso);
    float cr = cso, ci = sno;
#pragma unroll
    for (int m1 = 0; m1 < 16; ++m1) {
      const float xr = vr[m1], xi = vi[m1];
      vr[m1] = xr * cr - xi * ci;
      vi[m1] = xr * ci + xi * cr;
      const float nr = cr * csb - ci * snb, ni = cr * snb + ci * csb;
      cr = nr; ci = ni;
    }
  }
  tr_cross_inv(vr, vi, lds, t);
  dft16<1>(vr, vi);

  const int sl = bb * 2 + f;
  _Float16* upr = Urg + ((size_t)sl * C_N + c) * T_N;
  _Float16* upi = Uig + ((size_t)sl * C_N + c) * T_N;
#pragma unroll
  for (int n1 = 0; n1 < 16; ++n1) {
    const float ir = rsqrtf(vr[n1] * vr[n1] + vi[n1] * vi[n1] + 1e-6f);
    upr[n1 * 256 + t] = (_Float16)(vr[n1] * ir);
    upi[n1 * 256 + t] = (_Float16)(vi[n1] * ir);
  }
}

// ---------------- gram via f16 MFMA: Rr=UrUr^T, Ii=UiUi^T, Ri=UrUi^T ---------
__global__ __launch_bounds__(256) void gram_kernel(
    const _Float16* __restrict__ Urg, const _Float16* __restrict__ Uig,
    float* __restrict__ G, int slicebase) {
  const int sl = blockIdx.x >> 2;           // / TSG
  const int ts = blockIdx.x & (TSG - 1);
  const int tid = threadIdx.x;
  const int w = tid >> 6;
  const int lane = tid & 63;
  __shared__ _Float16 sUr[2][64 * 40], sUi[2][64 * 40];

  const int row = tid >> 2, quarter = tid & 3;
  const size_t goff = (size_t)sl * C_N * T_N + (size_t)row * T_N
                      + ts * (T_N / TSG) + quarter * 8;
  const int loff = row * 40 + quarter * 8;
  const int frow = (lane & 15) * 40 + (lane >> 4) * 8;
  const int aoff = w * 640 + frow;

  f32x4 accRr[4] = {}, accIi[4] = {}, accRi[4] = {};

  f16x8 rr = *(const f16x8*)&Urg[goff];
  f16x8 ri = *(const f16x8*)&Uig[goff];
  int cur = 0;
  for (int ks = 0; ks < NKS; ++ks) {
    *(f16x8*)&sUr[cur][loff] = rr;
    *(f16x8*)&sUi[cur][loff] = ri;
    if (ks + 1 < NKS) {
      rr = *(const f16x8*)&Urg[goff + (ks + 1) * 32];
      ri = *(const f16x8*)&Uig[goff + (ks + 1) * 32];
    }
    __syncthreads();
    const f16x8 ar = *(const f16x8*)&sUr[cur][aoff];
    const f16x8 ai = *(const f16x8*)&sUi[cur][aoff];
#pragma unroll
    for (int n = 0; n < 4; ++n) {
      const f16x8 br = *(const f16x8*)&sUr[cur][n * 640 + frow];
      const f16x8 bi = *(const f16x8*)&sUi[cur][n * 640 + frow];
      accRr[n] = __builtin_amdgcn_mfma_f32_16x16x32_f16(ar, br, accRr[n], 0, 0, 0);
      accIi[n] = __builtin_amdgcn_mfma_f32_16x16x32_f16(ai, bi, accIi[n], 0, 0, 0);
      accRi[n] = __builtin_amdgcn_mfma_f32_16x16x32_f16(ar, bi, accRi[n], 0, 0, 0);
    }
    cur ^= 1;
  }

  float* Gs = G + (size_t)(slicebase + sl) * 12288;
  const int r0 = w * 16 + (lane >> 4) * 4;
  const int c0 = lane & 15;
#pragma unroll
  for (int n = 0; n < 4; ++n) {
    const bool upper = (n >= w);   // skip strictly-below-diagonal Rr/Ii tiles
#pragma unroll
    for (int e = 0; e < 4; ++e) {
      const int idx = (r0 + e) * 64 + n * 16 + c0;
      if (upper) {
        atomicAdd(&Gs[idx], accRr[n][e]);
        atomicAdd(&Gs[4096 + idx], accIi[n][e]);
      }
      atomicAdd(&Gs[8192 + idx], accRi[n][e]);
    }
  }
}

// ---------------- PLV + scatter to feature layout ----------------
__global__ __launch_bounds__(256) void plv_kernel(
    const float* __restrict__ G, float* __restrict__ feats) {
  const int idx = blockIdx.x * 256 + threadIdx.x;
  if (idx >= B_N * NFILT * NPAIRS) return;
  const int slice = idx / NPAIRS;
  const int p = idx - slice * NPAIRS;
  const int b = slice >> 1, f = slice & 1;
  int c = 0, rem = p;
  while (rem >= 63 - c) { rem -= 63 - c; ++c; }
  const int d = c + 1 + rem;
  const float* Gs = G + (size_t)slice * 12288;
  const float cre = Gs[c * 64 + d] + Gs[4096 + c * 64 + d];        // rr + ii
  const float cim = Gs[8192 + c * 64 + d] - Gs[8192 + d * 64 + c]; // ri - ir
  const float plv = sqrtf(cre * cre + cim * cim + 1e-6f) * (1.0f / (float)T_N);
  feats[b * NFEAT + p * NFILT + f] = plv;
}

// ---------------- batch stats (training-mode BN, biased var) ----------------
__global__ __launch_bounds__(256) void stats_kernel(
    const float* __restrict__ feats, float* __restrict__ stats) {
  const int j = blockIdx.x * 256 + threadIdx.x;
  if (j >= NFEAT) return;
  float s = 0.0f;
  for (int b = 0; b < B_N; ++b) s += feats[b * NFEAT + j];
  const float mu = s * (1.0f / (float)B_N);
  float v = 0.0f;
  for (int b = 0; b < B_N; ++b) {
    const float d = feats[b * NFEAT + j] - mu;
    v += d * d;
  }
  v *= (1.0f / (float)B_N);
  stats[j] = mu;
  stats[NFEAT + j] = 1.0f / sqrtf(v + 1e-5f);
}

// ---------------- normalize + linear ----------------
__global__ __launch_bounds__(256) void out_kernel(
    const float* __restrict__ feats, const float* __restrict__ stats,
    const float* __restrict__ w, const float* __restrict__ lb,
    float* __restrict__ out) {
  const int b = blockIdx.x;
  const int tid = threadIdx.x;
  float acc0 = 0, acc1 = 0, acc2 = 0, acc3 = 0;
  for (int j = tid; j < NFEAT; j += 256) {
    const float v = (feats[b * NFEAT + j] - stats[j]) * stats[NFEAT + j];
    acc0 += v * w[0 * NFEAT + j];
    acc1 += v * w[1 * NFEAT + j];
    acc2 += v * w[2 * NFEAT + j];
    acc3 += v * w[3 * NFEAT + j];
  }
  __shared__ float red[4][256];
  red[0][tid] = acc0; red[1][tid] = acc1; red[2][tid] = acc2; red[3][tid] = acc3;
  __syncthreads();
  for (int s = 128; s > 0; s >>= 1) {
    if (tid < s) {
#pragma unroll
      for (int o = 0; o < 4; ++o) red[o][tid] += red[o][tid + s];
    }
    __syncthreads();
  }
  if (tid < 4) out[b * NOUT + tid] = red[tid][0] + lb[tid];
}

extern "C" void kernel_launch(void* const* d_in, const int* in_sizes, int n_in,
                              void* d_out, int out_size, void* d_ws, size_t ws_size,
                              hipStream_t stream) {
  const float* x  = (const float*)d_in[0];
  const float* fm = (const float*)d_in[1];
  const float* bw = (const float*)d_in[2];
  const float* sp = (const float*)d_in[3];
  const float* gd = (const float*)d_in[4];
  const float* lw = (const float*)d_in[5];
  const float* lb = (const float*)d_in[6];
  float* out = (float*)d_out;
  char* base = (char*)d_ws;

  // adaptive batch chunk: largest of {64,32,16} whose u-buffer fits ws
  const size_t fixed = 65536 + 6291456 + (size_t)B_N * NFEAT * 4 + 2 * NFEAT * 4;
  int CB = 64;
  if (ws_size < fixed + (size_t)64 * 2097152) CB = 32;
  if (ws_size < fixed + (size_t)32 * 2097152) CB = 16;
  const int nchunk = B_N / CB;

  const size_t u_bytes = (size_t)CB * 1048576;  // per component array
  float*    filt  = (float*)base;
  _Float16* Urg   = (_Float16*)(base + 65536);
  _Float16* Uig   = (_Float16*)(base + 65536 + u_bytes);
  float*    G     = (float*)(base + 65536 + 2 * u_bytes);
  float*    feats = (float*)(base + 65536 + 2 * u_bytes + 6291456);
  float*    stats = feats + (size_t)B_N * NFEAT;

  hipMemsetAsync(G, 0, 6291456, stream);
  filter_kernel<<<1, 256, 0, stream>>>(fm, bw, sp, gd, filt);

  for (int chunk = 0; chunk < nchunk; ++chunk) {
    fftfilt_kernel<<<CB * C_N * NFILT, 256, 0, stream>>>(x, filt, Urg, Uig, chunk * CB);
    gram_kernel<<<CB * 2 * TSG, 256, 0, stream>>>(Urg, Uig, G, chunk * CB * 2);
  }

  plv_kernel<<<(B_N * NFILT * NPAIRS + 255) / 256, 256, 0, stream>>>(G, feats);
  stats_kernel<<<(NFEAT + 255) / 256, 256, 0, stream>>>(feats, stats);
  out_kernel<<<B_N, 256, 0, stream>>>(feats, stats, lw, lb, out);
}

// Round 6
// 179.916 us; speedup vs baseline: 2.4827x; 1.1322x over previous
//
#include <hip/hip_runtime.h>
#include <math.h>

#define T_N     4096
#define B_N     64
#define C_N     64
#define NFILT   2
#define F_BINS  2049
#define NPAIRS  2016
#define NFEAT   4032
#define NOUT    4
#define TSG     4
#define NKS     32            // (4096/TSG)/32 K-steps per gram block

#define PI_F 3.14159265358979323846f

typedef _Float16 f16x8 __attribute__((ext_vector_type(8)));
typedef float    f32x4 __attribute__((ext_vector_type(4)));

// ---------------------------------------------------------------------------
// Spectrum layout of the 3-phase register FFT (N = 16*16*16):
//   thread t = k1*16 + j1, register q = j2  holds bin k = q*256 + j1*16 + k1.
// Filter table stored at p(k) = (k & 0xF00) + ((k & 15) << 4) + ((k >> 4) & 15).
// Twiddle tables (block-invariant, precomputed once):
//   T1[k*256+t] = e^{-2pi i t k/4096}            (fwd chain A)
//   T2[k*16+j]  = e^{-2pi i j k/256}             (fwd chain B; conj for inv B')
//   TC[m1*256+t]= e^{+2pi i k1(t)(m2(t)+16m1)/4096} (inv chain C)
// ---------------------------------------------------------------------------

// ---- ws layout (bytes) ----
#define OFF_T1    65536
#define OFF_TC    (OFF_T1 + 32768)
#define OFF_T2    (OFF_TC + 32768)
#define OFF_U     (OFF_T2 + 2048)          // 133120, 16B aligned
#define G_BYTES   (128 * TSG * 12288 * 4)  // 25165824

// ---------------- filter construction (1 block) ----------------
__global__ __launch_bounds__(256) void filter_kernel(
    const float* __restrict__ fm_, const float* __restrict__ bw_,
    const float* __restrict__ sp_, const float* __restrict__ gd_,
    float* __restrict__ filt) {
  __shared__ float smag[F_BINS];
  __shared__ float sred[256];
  const int tid = threadIdx.x;
  for (int f = 0; f < NFILT; ++f) {
    float* Fre = filt + f * 8192;
    float* Fim = Fre + 4096;
    for (int p = tid; p < 4096; p += 256) { Fre[p] = 0.0f; Fim[p] = 0.0f; }
    const float fm = fminf(fmaxf(fm_[f], 1.0f / 128.0f), 45.0f / 128.0f);
    const float bw = fminf(fmaxf(bw_[f], 1.0f / 128.0f), 1.0f);
    const float pp = fminf(fmaxf(sp_[f], 2.0f), 3.0f) * 8.0f - 14.0f;
    const float gd = gd_[f];
    const float scale = bw / (2.0f * powf(0.69314718055994531f, 1.0f / pp));
    float lmax = 0.0f;
    for (int i = tid; i < F_BINS; i += 256) {
      const float n = (float)i / 2048.0f;
      const float m = expf(-powf((fabsf(n - fm) + 1e-8f) / scale, pp));
      smag[i] = m;
      lmax = fmaxf(lmax, m);
    }
    sred[tid] = lmax;
    __syncthreads();
    for (int s = 128; s > 0; s >>= 1) {
      if (tid < s) sred[tid] = fmaxf(sred[tid], sred[tid + s]);
      __syncthreads();
    }
    const float inv = 1.0f / sred[0];
    __syncthreads();
    for (int k = tid; k < F_BINS; k += 256) {
      const float m = smag[k] * inv;
      const float pha = -gd * ((float)k * 0.125f) * PI_F;
      float sn, cs;
      sincosf(pha, &sn, &cs);
      const float dcs = (k == 0) ? 1.0f : 2.0f;
      const float sT = dcs * (1.0f / (float)T_N);
      const int p = (k & 0xF00) + ((k & 15) << 4) + ((k >> 4) & 15);
      Fre[p] = m * cs * sT;
      Fim[p] = m * sn * sT;
    }
    __syncthreads();
  }
}

// ---------------- twiddle tables (one-time) ----------------
__global__ __launch_bounds__(256) void twiddle_kernel(
    float2* __restrict__ T1, float2* __restrict__ TC, float2* __restrict__ T2) {
  const int g = blockIdx.x * 256 + threadIdx.x;
  if (blockIdx.x < 16) {
    const int k = g >> 8, t = g & 255;
    float sn, cs;
    sincosf(-2.0f * PI_F * (float)(t * k) * (1.0f / 4096.0f), &sn, &cs);
    T1[g] = make_float2(cs, sn);
    if (g < 256) {
      const int kk = g >> 4, j = g & 15;
      float sn2, cs2;
      sincosf(-2.0f * PI_F * (float)(j * kk) * (1.0f / 256.0f), &sn2, &cs2);
      T2[g] = make_float2(cs2, sn2);
    }
  } else {
    const int g2 = g - 4096;
    const int m1 = g2 >> 8, t = g2 & 255;
    const int k1 = t >> 4, m2 = t & 15;
    float sn, cs;
    sincosf(2.0f * PI_F * (float)(k1 * (m2 + 16 * m1)) * (1.0f / 4096.0f), &sn, &cs);
    TC[g2] = make_float2(cs, sn);
  }
}

// ---------------- 16-point DFT, natural order in/out, in registers ----------
template<int SGN>
__device__ __forceinline__ void dft16(float* __restrict__ vr,
                                      float* __restrict__ vi) {
  const float sg = (float)SGN;
  const float C1 = 0.923879532511287f, S1 = 0.382683432365090f;
  const float Hh = 0.707106781186548f;
  float gr[16], gi[16];
#pragma unroll
  for (int n2 = 0; n2 < 4; ++n2) {
    const float ar = vr[n2],      ai = vi[n2];
    const float br = vr[4 + n2],  bi = vi[4 + n2];
    const float cr = vr[8 + n2],  ci = vi[8 + n2];
    const float dr = vr[12 + n2], di = vi[12 + n2];
    const float t0r = ar + cr, t0i = ai + ci;
    const float t1r = ar - cr, t1i = ai - ci;
    const float t2r = br + dr, t2i = bi + di;
    const float t3r = br - dr, t3i = bi - di;
    gr[n2]      = t0r + t2r;      gi[n2]      = t0i + t2i;
    gr[4 + n2]  = t1r - sg * t3i; gi[4 + n2]  = t1i + sg * t3r;
    gr[8 + n2]  = t0r - t2r;      gi[8 + n2]  = t0i - t2i;
    gr[12 + n2] = t1r + sg * t3i; gi[12 + n2] = t1i - sg * t3r;
  }
#define TW16(idx, wr_, wi_) { const float xr = gr[idx], xi = gi[idx]; \
    gr[idx] = xr * (wr_) - xi * (wi_); gi[idx] = xr * (wi_) + xi * (wr_); }
  TW16(5,  C1,  sg * S1)
  TW16(6,  Hh,  sg * Hh)
  TW16(7,  S1,  sg * C1)
  TW16(9,  Hh,  sg * Hh)
  { const float xr = gr[10], xi = gi[10];
    gr[10] = -sg * xi; gi[10] = sg * xr; }
  TW16(11, -Hh, sg * Hh)
  TW16(13, S1,  sg * C1)
  TW16(14, -Hh, sg * Hh)
  TW16(15, -C1, -sg * S1)
#undef TW16
#pragma unroll
  for (int k1 = 0; k1 < 4; ++k1) {
    const float ar = gr[4 * k1],     ai = gi[4 * k1];
    const float br = gr[4 * k1 + 1], bi = gi[4 * k1 + 1];
    const float cr = gr[4 * k1 + 2], ci = gi[4 * k1 + 2];
    const float dr = gr[4 * k1 + 3], di = gi[4 * k1 + 3];
    const float t0r = ar + cr, t0i = ai + ci;
    const float t1r = ar - cr, t1i = ai - ci;
    const float t2r = br + dr, t2i = bi + di;
    const float t3r = br - dr, t3i = bi - di;
    vr[k1]      = t0r + t2r;      vi[k1]      = t0i + t2i;
    vr[4 + k1]  = t1r - sg * t3i; vi[4 + k1]  = t1i + sg * t3r;
    vr[8 + k1]  = t0r - t2r;      vi[8 + k1]  = t0i - t2i;
    vr[12 + k1] = t1r + sg * t3i; vi[12 + k1] = t1i - sg * t3r;
  }
}

// transposes through padded float2 LDS (stride 264 -> ~2-way banks)
__device__ __forceinline__ void tr_cross_fwd(float* __restrict__ vr,
                                             float* __restrict__ vi,
                                             float2* __restrict__ lds, int t) {
  __syncthreads();
#pragma unroll
  for (int k = 0; k < 16; ++k) lds[k * 264 + t] = make_float2(vr[k], vi[k]);
  __syncthreads();
  const int base = (t >> 4) * 264 + (t & 15);
#pragma unroll
  for (int m = 0; m < 16; ++m) {
    const float2 v = lds[base + m * 16];
    vr[m] = v.x; vi[m] = v.y;
  }
}
__device__ __forceinline__ void tr_cross_inv(float* __restrict__ vr,
                                             float* __restrict__ vi,
                                             float2* __restrict__ lds, int t) {
  __syncthreads();
  const int base = (t >> 4) * 264 + (t & 15);
#pragma unroll
  for (int m = 0; m < 16; ++m) lds[base + m * 16] = make_float2(vr[m], vi[m]);
  __syncthreads();
#pragma unroll
  for (int k = 0; k < 16; ++k) {
    const float2 v = lds[k * 264 + t];
    vr[k] = v.x; vi[k] = v.y;
  }
}
__device__ __forceinline__ void tr_group(float* __restrict__ vr,
                                         float* __restrict__ vi,
                                         float2* __restrict__ lds, int t) {
  __syncthreads();
  const int k1 = t >> 4, s = t & 15;
  const int rowb = k1 * 264;
#pragma unroll
  for (int r = 0; r < 16; ++r)
    lds[rowb + r * 16 + ((s + r) & 15)] = make_float2(vr[r], vi[r]);
  __syncthreads();
#pragma unroll
  for (int a = 0; a < 16; ++a) {
    const float2 v = lds[rowb + s * 16 + ((a + s) & 15)];
    vr[a] = v.x; vi[a] = v.y;
  }
}

// ---------------- fwd FFT once + filter + 2x inverse FFT + normalize --------
// X cached in 32 VGPRs; no min-waves bound (r4's forced bound caused spills).
__global__ __launch_bounds__(256) void fftfilt_kernel(
    const float* __restrict__ x, const float* __restrict__ filt,
    const float2* __restrict__ T1g, const float2* __restrict__ TCg,
    const float2* __restrict__ T2g,
    _Float16* __restrict__ Urg, _Float16* __restrict__ Uig, int chunkbase) {
  const int c  = blockIdx.x & 63;
  const int bb = blockIdx.x >> 6;
  const int b  = chunkbase + bb;
  const int t  = threadIdx.x;
  const int j1 = t & 15;
  __shared__ float2 lds[16 * 264];   // 33792 B

  float vr[16], vi[16];
  const float* xp = x + ((size_t)(b * C_N + c)) * T_N;
#pragma unroll
  for (int r = 0; r < 16; ++r) { vr[r] = xp[r * 256 + t]; vi[r] = 0.0f; }

  // ---- forward ----
  dft16<-1>(vr, vi);
#pragma unroll
  for (int k = 1; k < 16; ++k) {               // chain A: *T1[k][t]
    const float2 w = T1g[k * 256 + t];
    const float xr = vr[k], xi = vi[k];
    vr[k] = xr * w.x - xi * w.y;
    vi[k] = xr * w.y + xi * w.x;
  }
  tr_cross_fwd(vr, vi, lds, t);
  dft16<-1>(vr, vi);
#pragma unroll
  for (int k = 1; k < 16; ++k) {               // chain B: *T2[k][j1]
    const float2 w = T2g[k * 16 + j1];
    const float xr = vr[k], xi = vi[k];
    vr[k] = xr * w.x - xi * w.y;
    vi[k] = xr * w.y + xi * w.x;
  }
  tr_group(vr, vi, lds, t);
  dft16<-1>(vr, vi);

  float Xr[16], Xi[16];
#pragma unroll
  for (int q = 0; q < 16; ++q) { Xr[q] = vr[q]; Xi[q] = vi[q]; }

#pragma unroll 1
  for (int f = 0; f < NFILT; ++f) {
    const float* Fre = filt + f * 8192;
    const float* Fim = Fre + 4096;
#pragma unroll
    for (int q = 0; q < 16; ++q) {
      vr[q] = Xr[q] * Fre[q * 256 + t];        // component-wise filter
      vi[q] = Xi[q] * Fim[q * 256 + t];
    }
    // ---- inverse (mirror dataflow, conj twiddles, unscaled) ----
    dft16<1>(vr, vi);
#pragma unroll
    for (int k = 1; k < 16; ++k) {             // chain B': *conj(T2[k][j1])
      const float2 w = T2g[k * 16 + j1];
      const float xr = vr[k], xi = vi[k];
      vr[k] = xr * w.x + xi * w.y;
      vi[k] = xi * w.x - xr * w.y;
    }
    tr_group(vr, vi, lds, t);
    dft16<1>(vr, vi);
#pragma unroll
    for (int m1 = 0; m1 < 16; ++m1) {          // chain C: *TC[m1][t]
      const float2 w = TCg[m1 * 256 + t];
      const float xr = vr[m1], xi = vi[m1];
      vr[m1] = xr * w.x - xi * w.y;
      vi[m1] = xr * w.y + xi * w.x;
    }
    tr_cross_inv(vr, vi, lds, t);
    dft16<1>(vr, vi);

    const int sl = bb * 2 + f;
    _Float16* upr = Urg + ((size_t)sl * C_N + c) * T_N;
    _Float16* upi = Uig + ((size_t)sl * C_N + c) * T_N;
#pragma unroll
    for (int n1 = 0; n1 < 16; ++n1) {
      const float ir = rsqrtf(vr[n1] * vr[n1] + vi[n1] * vi[n1] + 1e-6f);
      upr[n1 * 256 + t] = (_Float16)(vr[n1] * ir);
      upi[n1 * 256 + t] = (_Float16)(vi[n1] * ir);
    }
  }
}

// ---------------- gram via f16 MFMA -> per-tsplit partial planes ------------
__global__ __launch_bounds__(256) void gram_kernel(
    const _Float16* __restrict__ Urg, const _Float16* __restrict__ Uig,
    float* __restrict__ Gp, int slicebase) {
  const int sl = blockIdx.x >> 2;           // / TSG
  const int ts = blockIdx.x & (TSG - 1);
  const int tid = threadIdx.x;
  const int w = tid >> 6;
  const int lane = tid & 63;
  __shared__ _Float16 sUr[2][64 * 40], sUi[2][64 * 40];

  const int row = tid >> 2, quarter = tid & 3;
  const size_t goff = (size_t)sl * C_N * T_N + (size_t)row * T_N
                      + ts * (T_N / TSG) + quarter * 8;
  const int loff = row * 40 + quarter * 8;
  const int frow = (lane & 15) * 40 + (lane >> 4) * 8;
  const int aoff = w * 640 + frow;

  f32x4 accRr[4] = {}, accIi[4] = {}, accRi[4] = {};

  f16x8 rr = *(const f16x8*)&Urg[goff];
  f16x8 ri = *(const f16x8*)&Uig[goff];
  int cur = 0;
  for (int ks = 0; ks < NKS; ++ks) {
    *(f16x8*)&sUr[cur][loff] = rr;
    *(f16x8*)&sUi[cur][loff] = ri;
    if (ks + 1 < NKS) {
      rr = *(const f16x8*)&Urg[goff + (ks + 1) * 32];
      ri = *(const f16x8*)&Uig[goff + (ks + 1) * 32];
    }
    __syncthreads();
    const f16x8 ar = *(const f16x8*)&sUr[cur][aoff];
    const f16x8 ai = *(const f16x8*)&sUi[cur][aoff];
#pragma unroll
    for (int n = 0; n < 4; ++n) {
      const f16x8 br = *(const f16x8*)&sUr[cur][n * 640 + frow];
      const f16x8 bi = *(const f16x8*)&sUi[cur][n * 640 + frow];
      accRr[n] = __builtin_amdgcn_mfma_f32_16x16x32_f16(ar, br, accRr[n], 0, 0, 0);
      accIi[n] = __builtin_amdgcn_mfma_f32_16x16x32_f16(ai, bi, accIi[n], 0, 0, 0);
      accRi[n] = __builtin_amdgcn_mfma_f32_16x16x32_f16(ar, bi, accRi[n], 0, 0, 0);
    }
    cur ^= 1;
  }

  // plain stores into this block's own partial plane (no atomics)
  float* Gs = Gp + (size_t)((slicebase + sl) * TSG + ts) * 12288;
  const int r0 = w * 16 + (lane >> 4) * 4;
  const int c0 = lane & 15;
#pragma unroll
  for (int n = 0; n < 4; ++n) {
    const bool upper = (n >= w);   // strictly-below-diagonal Rr/Ii never read
#pragma unroll
    for (int e = 0; e < 4; ++e) {
      const int idx = (r0 + e) * 64 + n * 16 + c0;
      if (upper) {
        Gs[idx] = accRr[n][e];
        Gs[4096 + idx] = accIi[n][e];
      }
      Gs[8192 + idx] = accRi[n][e];
    }
  }
}

// ---------------- PLV (sums TSG partials) + scatter to feature layout -------
__global__ __launch_bounds__(256) void plv_kernel(
    const float* __restrict__ Gp, float* __restrict__ feats) {
  const int idx = blockIdx.x * 256 + threadIdx.x;
  if (idx >= B_N * NFILT * NPAIRS) return;
  const int slice = idx / NPAIRS;
  const int p = idx - slice * NPAIRS;
  const int b = slice >> 1, f = slice & 1;
  int c = 0, rem = p;
  while (rem >= 63 - c) { rem -= 63 - c; ++c; }
  const int d = c + 1 + rem;
  const float* Gs = Gp + (size_t)slice * TSG * 12288;
  float rr = 0, ii = 0, ri = 0, ir = 0;
#pragma unroll
  for (int ts = 0; ts < TSG; ++ts) {
    const float* P = Gs + ts * 12288;
    rr += P[c * 64 + d];
    ii += P[4096 + c * 64 + d];
    ri += P[8192 + c * 64 + d];
    ir += P[8192 + d * 64 + c];
  }
  const float cre = rr + ii;
  const float cim = ri - ir;
  const float plv = sqrtf(cre * cre + cim * cim + 1e-6f) * (1.0f / (float)T_N);
  feats[b * NFEAT + p * NFILT + f] = plv;
}

// ---------------- batch stats (training-mode BN, biased var) ----------------
__global__ __launch_bounds__(256) void stats_kernel(
    const float* __restrict__ feats, float* __restrict__ stats) {
  const int j = blockIdx.x * 256 + threadIdx.x;
  if (j >= NFEAT) return;
  float s = 0.0f;
  for (int b = 0; b < B_N; ++b) s += feats[b * NFEAT + j];
  const float mu = s * (1.0f / (float)B_N);
  float v = 0.0f;
  for (int b = 0; b < B_N; ++b) {
    const float d = feats[b * NFEAT + j] - mu;
    v += d * d;
  }
  v *= (1.0f / (float)B_N);
  stats[j] = mu;
  stats[NFEAT + j] = 1.0f / sqrtf(v + 1e-5f);
}

// ---------------- normalize + linear ----------------
__global__ __launch_bounds__(256) void out_kernel(
    const float* __restrict__ feats, const float* __restrict__ stats,
    const float* __restrict__ w, const float* __restrict__ lb,
    float* __restrict__ out) {
  const int b = blockIdx.x;
  const int tid = threadIdx.x;
  float acc0 = 0, acc1 = 0, acc2 = 0, acc3 = 0;
  for (int j = tid; j < NFEAT; j += 256) {
    const float v = (feats[b * NFEAT + j] - stats[j]) * stats[NFEAT + j];
    acc0 += v * w[0 * NFEAT + j];
    acc1 += v * w[1 * NFEAT + j];
    acc2 += v * w[2 * NFEAT + j];
    acc3 += v * w[3 * NFEAT + j];
  }
  __shared__ float red[4][256];
  red[0][tid] = acc0; red[1][tid] = acc1; red[2][tid] = acc2; red[3][tid] = acc3;
  __syncthreads();
  for (int s = 128; s > 0; s >>= 1) {
    if (tid < s) {
#pragma unroll
      for (int o = 0; o < 4; ++o) red[o][tid] += red[o][tid + s];
    }
    __syncthreads();
  }
  if (tid < 4) out[b * NOUT + tid] = red[tid][0] + lb[tid];
}

extern "C" void kernel_launch(void* const* d_in, const int* in_sizes, int n_in,
                              void* d_out, int out_size, void* d_ws, size_t ws_size,
                              hipStream_t stream) {
  const float* x  = (const float*)d_in[0];
  const float* fm = (const float*)d_in[1];
  const float* bw = (const float*)d_in[2];
  const float* sp = (const float*)d_in[3];
  const float* gd = (const float*)d_in[4];
  const float* lw = (const float*)d_in[5];
  const float* lb = (const float*)d_in[6];
  float* out = (float*)d_out;
  char* base = (char*)d_ws;

  // adaptive batch chunk: largest of {64,32,16} that fits ws
  const size_t fixed = OFF_U + (size_t)G_BYTES + (size_t)B_N * NFEAT * 4 + 2 * NFEAT * 4;
  int CB = 64;
  if (ws_size < fixed + (size_t)64 * 2097152) CB = 32;
  if (ws_size < fixed + (size_t)32 * 2097152) CB = 16;
  const int nchunk = B_N / CB;

  const size_t u_bytes = (size_t)CB * 1048576;  // per component array
  float*    filt  = (float*)base;
  float2*   T1    = (float2*)(base + OFF_T1);
  float2*   TC    = (float2*)(base + OFF_TC);
  float2*   T2    = (float2*)(base + OFF_T2);
  _Float16* Urg   = (_Float16*)(base + OFF_U);
  _Float16* Uig   = (_Float16*)(base + OFF_U + u_bytes);
  float*    Gp    = (float*)(base + OFF_U + 2 * u_bytes);
  float*    feats = (float*)(base + OFF_U + 2 * u_bytes + G_BYTES);
  float*    stats = feats + (size_t)B_N * NFEAT;

  filter_kernel<<<1, 256, 0, stream>>>(fm, bw, sp, gd, filt);
  twiddle_kernel<<<32, 256, 0, stream>>>(T1, TC, T2);

  for (int chunk = 0; chunk < nchunk; ++chunk) {
    fftfilt_kernel<<<CB * C_N, 256, 0, stream>>>(x, filt, T1, TC, T2,
                                                 Urg, Uig, chunk * CB);
    gram_kernel<<<CB * 2 * TSG, 256, 0, stream>>>(Urg, Uig, Gp, chunk * CB * 2);
  }

  plv_kernel<<<(B_N * NFILT * NPAIRS + 255) / 256, 256, 0, stream>>>(Gp, feats);
  stats_kernel<<<(NFEAT + 255) / 256, 256, 0, stream>>>(feats, stats);
  out_kernel<<<B_N, 256, 0, stream>>>(feats, stats, lw, lb, out);
}